// Round 3
// baseline (1346.509 us; speedup 1.0000x reference)
//
#include <hip/hip_runtime.h>
#include <hip/hip_bf16.h>

// Problem constants
#define NB     32
#define CDIM   256
#define HWDIM  1024          // 32*32
#define NROWS  32768         // NB*HWDIM
#define NE     8192
#define PANELS 4
#define COLS_PER_PANEL 2048
#define NT_PER_PANEL   16    // 2048/128

// numpy pairwise-sum variant for A = np.sum(zf*zf, axis=1):
// 0 = fixed-order scalar 8-accumulator (ISA-independent numpy kernel)
// 1 = npyv AVX512 + gcc _mm512_reduce_add_ps tree
#define NP_SUM_VARIANT 0

typedef float f32x4 __attribute__((ext_vector_type(4)));
typedef short bf16x8 __attribute__((ext_vector_type(8)));

// d_out layout (floats): z_q_out | loss | d | indices
#define OUT_ZQ   0ull
#define OUT_LOSS 8388608ull
#define OUT_D    8388609ull
#define OUT_IDX  276824065ull   // 8388609 + 32768*8192

// workspace layout (bytes)
#define WS_ZF    0ull           // [NROWS][256] bf16 (16 MB)
#define WS_EMB   16777216ull    // [NE][256] bf16 (4 MB)
#define WS_ASUM  20971520ull    // [NROWS] f32
#define WS_BSUM  21102592ull    // [NE] f32
#define WS_PMIN  21135360ull    // [PANELS][NROWS] u64 packed (val,idx)
#define WS_IDX   22183936ull    // [NROWS] i32
#define WS_DMIN  22315008ull    // [NROWS] f32
#define WS_LOSS  22446080ull    // f32 accumulator

#define REFINE_DELTA 2e-3f

typedef __attribute__((address_space(1))) const void global_cvoid;
typedef __attribute__((address_space(3))) void lds_void;

__device__ __forceinline__ void gl_lds16(const void* g, void* l) {
  __builtin_amdgcn_global_load_lds((global_cvoid*)g, (lds_void*)l, 16, 0, 0);
}

// ---- prep: transpose z[b][c][hw] -> zf[n][c] (bf16), n = b*1024 + hw ----
__global__ void k_prep_zf(const float* __restrict__ z, __hip_bfloat16* __restrict__ zf) {
  __shared__ float tile[32][33];
  const int b   = blockIdx.z;
  const int c0  = blockIdx.y * 32;
  const int hw0 = blockIdx.x * 32;
  const int tx  = threadIdx.x & 31;
  const int ty  = threadIdx.x >> 5;   // 0..7
  const float* zb = z + (size_t)b * (CDIM * HWDIM);
#pragma unroll
  for (int i = 0; i < 4; ++i) {
    int c = ty + i * 8;
    tile[c][tx] = zb[(size_t)(c0 + c) * HWDIM + hw0 + tx];
  }
  __syncthreads();
#pragma unroll
  for (int i = 0; i < 4; ++i) {
    int row = ty + i * 8;                 // hw-local
    int n = b * HWDIM + hw0 + row;
    zf[(size_t)n * CDIM + c0 + tx] = __float2bfloat16(tile[tx][row]);
  }
}

// ---- prep: A~[n] = sum_c z[n][c]^2 (fast fp32, used only for stored d~) ----
__global__ void k_prep_asum(const float* __restrict__ z, float* __restrict__ asum) {
  const int t   = threadIdx.x;
  const int blk = blockIdx.x;           // 0..127
  const int b   = blk >> 2;
  const int hw0 = (blk & 3) * 256;
  const float* zb = z + (size_t)b * (CDIM * HWDIM) + hw0 + t;
  float s = 0.f;
  for (int c = 0; c < CDIM; ++c) {
    float v = zb[(size_t)c * HWDIM];
    s = fmaf(v, v, s);
  }
  asum[b * HWDIM + hw0 + t] = s;
}

// ---- prep: emb -> bf16, B[e] = sum_c e^2 (fp32) ----
__global__ void k_prep_emb(const float* __restrict__ emb, __hip_bfloat16* __restrict__ embb,
                           float* __restrict__ bsum) {
  const int t = threadIdx.x, lane = t & 63, w = t >> 6;
  const int row = blockIdx.x * 4 + w;
  const float4 v = ((const float4*)(emb + (size_t)row * CDIM))[lane];
  __hip_bfloat16* dst = embb + (size_t)row * CDIM + lane * 4;
  dst[0] = __float2bfloat16(v.x);
  dst[1] = __float2bfloat16(v.y);
  dst[2] = __float2bfloat16(v.z);
  dst[3] = __float2bfloat16(v.w);
  float s = v.x * v.x + v.y * v.y + v.z * v.z + v.w * v.w;
#pragma unroll
  for (int m = 32; m; m >>= 1) s += __shfl_xor(s, m, 64);
  if (lane == 0) bsum[row] = s;
}

// ---- GEMM + d-write + per-row packed argmin (panel-partial) ----
__global__ __launch_bounds__(256) void k_gemm(
    const __hip_bfloat16* __restrict__ zf, const __hip_bfloat16* __restrict__ embb,
    const float* __restrict__ asum, const float* __restrict__ bsum,
    float* __restrict__ dmat,                       // d region base
    unsigned long long* __restrict__ pmin) {
  __shared__ __hip_bfloat16 As[128 * 64];
  __shared__ __hip_bfloat16 Bs[128 * 64];
  __shared__ unsigned long long smin[128];
  __shared__ unsigned long long smin2[2][128];

  const int tid = threadIdx.x;
  const int lane = tid & 63;
  const int w = tid >> 6;
  const int wr = w >> 1, wc = w & 1;
  const int l15 = lane & 15, g = lane >> 4;
  const int row0 = blockIdx.x * 128;
  const int colp = blockIdx.y * COLS_PER_PANEL;

  if (tid < 128) smin[tid] = ~0ull;

  float av[4][4];
#pragma unroll
  for (int m = 0; m < 4; ++m) {
    const f32x4 a4 = *(const f32x4*)(asum + row0 + wr * 64 + m * 16 + g * 4);
#pragma unroll
    for (int r = 0; r < 4; ++r) av[m][r] = a4[r];
  }

  for (int nt = 0; nt < NT_PER_PANEL; ++nt) {
    const int col0 = colp + nt * 128;
    f32x4 acc[4][4];
#pragma unroll
    for (int m = 0; m < 4; ++m)
#pragma unroll
      for (int n = 0; n < 4; ++n) acc[m][n] = (f32x4){0.f, 0.f, 0.f, 0.f};

    float bv[4];
#pragma unroll
    for (int n = 0; n < 4; ++n) bv[n] = bsum[col0 + wc * 64 + n * 16 + l15];

    for (int ks = 0; ks < 4; ++ks) {
      const int k0 = ks * 64;
#pragma unroll
      for (int I = 0; I < 4; ++I) {
        const int boff = I * 4096 + tid * 16;
        const int r  = boff >> 7;         // 128 B per row
        const int ch = (boff >> 4) & 7;   // 16B chunk in row
        gl_lds16((const char*)zf   + (size_t)(row0 + r) * 512 + k0 * 2 + ch * 16,
                 (char*)As + boff);
        gl_lds16((const char*)embb + (size_t)(col0 + r) * 512 + k0 * 2 + ch * 16,
                 (char*)Bs + boff);
      }
      __syncthreads();
#pragma unroll
      for (int kk = 0; kk < 2; ++kk) {
        bf16x8 af[4], bfr[4];
#pragma unroll
        for (int m = 0; m < 4; ++m)
          af[m] = *(const bf16x8*)((const char*)As + (wr * 64 + m * 16 + l15) * 128 + kk * 64 + g * 16);
#pragma unroll
        for (int n = 0; n < 4; ++n)
          bfr[n] = *(const bf16x8*)((const char*)Bs + (wc * 64 + n * 16 + l15) * 128 + kk * 64 + g * 16);
#pragma unroll
        for (int m = 0; m < 4; ++m)
#pragma unroll
          for (int n = 0; n < 4; ++n)
            acc[m][n] = __builtin_amdgcn_mfma_f32_16x16x32_bf16(af[m], bfr[n], acc[m][n], 0, 0, 0);
      }
      __syncthreads();
    }

#pragma unroll
    for (int m = 0; m < 4; ++m) {
#pragma unroll
      for (int r = 0; r < 4; ++r) {
        const int rowL = wr * 64 + m * 16 + g * 4 + r;
        const size_t rowbase = (size_t)(row0 + rowL) * NE;
        unsigned long long key = ~0ull;
#pragma unroll
        for (int n = 0; n < 4; ++n) {
          const int col = col0 + wc * 64 + n * 16 + l15;
          const float c = acc[m][n][r];
          const float t = av[m][r] + bv[n];
          const float dv = fmaf(-2.f, c, t);    // t - 2c
          dmat[rowbase + col] = dv;
          unsigned long long k2 =
              ((unsigned long long)__float_as_uint(dv) << 32) | (unsigned)col;
          key = k2 < key ? k2 : key;
        }
#pragma unroll
        for (int s = 1; s < 16; s <<= 1) {
          unsigned long long o = __shfl_xor(key, s, 64);
          key = o < key ? o : key;
        }
        if (l15 == 0) smin2[wc][rowL] = key;
      }
    }
    __syncthreads();
    if (tid < 128) {
      unsigned long long a = smin2[0][tid], b = smin2[1][tid];
      unsigned long long mk = a < b ? a : b;
      if (mk < smin[tid]) smin[tid] = mk;
    }
    __syncthreads();
  }
  if (tid < 128) pmin[(size_t)blockIdx.y * NROWS + row0 + tid] = smin[tid];
}

// ---- combine panel argmins -> per-row min stored-d value (f32) ----
__global__ void k_combine_dmin(const unsigned long long* __restrict__ pmin,
                               float* __restrict__ dminf) {
  const int n = blockIdx.x * 256 + threadIdx.x;
  unsigned long long k = pmin[n];
#pragma unroll
  for (int p = 1; p < PANELS; ++p) {
    unsigned long long o = pmin[(size_t)p * NROWS + n];
    k = o < k ? o : k;
  }
  dminf[n] = __uint_as_float((unsigned)(k >> 32));
}

// ---- refine: replicate numpy f32 argmin exactly ----
// np: d_e = fl32(A - 2*C_e)  (B < ULP/2 vanishes in fl(A+B))
// A  = np.sum(zf*zf, axis=1) pairwise f32 (bit-exact tree below)
// C_e rounded to f32 from exact f64 dot (np einsum error ~1e-9 only
// matters within ~1e-9 of a bucket edge: ~0.2 expected rows)
// winner = lowest e among argmin buckets (np first-index tie-break)
__global__ __launch_bounds__(256) void k_refine(
    const float* __restrict__ dmat, const float* __restrict__ dminf,
    const float* __restrict__ z, const float* __restrict__ emb,
    float* __restrict__ out_idx, int* __restrict__ idx_i) {
  __shared__ float zrow[4][CDIM];
  __shared__ float zsq[4][CDIM];
  const int w = threadIdx.x >> 6, lane = threadIdx.x & 63;
  const int n = blockIdx.x * 4 + w;
  const int b = n >> 10, hw = n & 1023;

  const float* zb = z + (size_t)b * (CDIM * HWDIM) + hw;
#pragma unroll
  for (int j = 0; j < 4; ++j) {
    const float v = zb[(size_t)(lane * 4 + j) * HWDIM];
    zrow[w][lane * 4 + j] = v;
    zsq[w][lane * 4 + j] = v * v;   // RNE mul; LDS round-trip blocks fma-contraction
  }
  __syncthreads();

  // ---- A: numpy pairwise f32, n=256 -> two 128 blocks, each 8-accumulator ----
  float A;
#if NP_SUM_VARIANT == 0
  {
    const float* x = zsq[w];
    const int base = (lane & 8) ? 128 : 0;   // lane groups: 0-7 half0, 8-15 half1
    const int j = lane & 7;
    float r = x[base + j];
#pragma unroll
    for (int i = 8; i < 128; i += 8) r += x[base + i + j];
    // ((r0+r1)+(r2+r3)) + ((r4+r5)+(r6+r7))
    r += __shfl_xor(r, 1, 64);
    r += __shfl_xor(r, 2, 64);
    r += __shfl_xor(r, 4, 64);
    const float h0 = __shfl(r, 0, 64);
    const float h1 = __shfl(r, 8, 64);
    A = h0 + h1;
  }
#else
  {
    // npyv AVX512: 4 vec accumulators (16 lanes), then gcc reduce tree
    const float* x = zsq[w];
    const int base = (lane & 16) ? 128 : 0;  // lanes 0-15 half0, 16-31 half1
    const int l = lane & 15;
    float s[4];
#pragma unroll
    for (int k = 0; k < 4; ++k)
      s[k] = x[base + 16 * k + l] + x[base + 64 + 16 * k + l];
    float v01 = s[0] + s[1], v23 = s[2] + s[3];
    float r = v01 + v23;
    // gcc _mm512_reduce_add_ps: l^8, l^4, l^1, l^2
    r += __shfl_xor(r, 8, 64);
    r += __shfl_xor(r, 4, 64);
    r += __shfl_xor(r, 1, 64);
    r += __shfl_xor(r, 2, 64);
    const float h0 = __shfl(r, 0, 64);
    const float h1 = __shfl(r, 16, 64);
    A = h0 + h1;
  }
#endif

  // ---- candidate scan over stored d~, exact bucket argmin ----
  const float thresh = dminf[n] + REFINE_DELTA;
  const float* drow = dmat + (size_t)n * NE;
  const float* zr = &zrow[w][lane * 4];
  unsigned long long best = ~0ull;

  for (int i = 0; i < NE / 64; ++i) {
    const int colbase = i * 64;
    const float v = drow[colbase + lane];
    unsigned long long mask = __ballot(v <= thresh);
    while (mask) {
      const int bpos = (int)__builtin_ctzll(mask);
      mask &= mask - 1;
      const int col = colbase + bpos;
      // 64-lane exact f64 dot: C = z . e
      const float4 ev = ((const float4*)(emb + (size_t)col * CDIM))[lane];
      double acc = (double)zr[0] * (double)ev.x;
      acc = fma((double)zr[1], (double)ev.y, acc);
      acc = fma((double)zr[2], (double)ev.z, acc);
      acc = fma((double)zr[3], (double)ev.w, acc);
#pragma unroll
      for (int s = 1; s < 64; s <<= 1) acc += __shfl_xor(acc, s, 64);
      const float C32 = (float)acc;         // RNE f64->f32
      const float D = A - 2.0f * C32;       // np: fl(A - 2C); fma contraction safe (2C exact)
      const unsigned long long key =
          ((unsigned long long)__float_as_uint(D) << 32) | (unsigned)col;
      if (key < best) best = key;
    }
  }
  if (lane == 0) {
    const int bi = (int)(unsigned)(best & 0xffffffffull);
    idx_i[n] = bi;
    out_idx[n] = (float)bi;
  }
}

// ---- gather z_q, straight-through output, loss partial ----
__global__ void k_gather(const float* __restrict__ z, const float* __restrict__ emb,
                         const int* __restrict__ idx_i, float* __restrict__ zq_out,
                         float* __restrict__ loss_acc) {
  float part = 0.f;
  const unsigned stride = gridDim.x * 256u;
  for (unsigned i = blockIdx.x * 256u + threadIdx.x; i < 8388608u; i += stride) {
    const int hw = i & 1023;
    const int c  = (i >> 10) & 255;
    const int b  = i >> 18;
    const int n  = b * HWDIM + hw;
    const int e  = idx_i[n];
    const float zq = emb[(size_t)e * CDIM + c];
    const float zv = z[i];
    zq_out[i] = zv + (zq - zv);       // straight-through, ref rounding order
    const float df = zq - zv;
    part = fmaf(df, df, part);
  }
#pragma unroll
  for (int s = 32; s; s >>= 1) part += __shfl_xor(part, s, 64);
  __shared__ float wsum[4];
  if ((threadIdx.x & 63) == 0) wsum[threadIdx.x >> 6] = part;
  __syncthreads();
  if (threadIdx.x == 0) atomicAdd(loss_acc, wsum[0] + wsum[1] + wsum[2] + wsum[3]);
}

__global__ void k_loss_final(const float* __restrict__ loss_acc, float* __restrict__ out_loss) {
  const float m = *loss_acc / 8388608.0f;
  *out_loss = m + 0.25f * m;
}

extern "C" void kernel_launch(void* const* d_in, const int* in_sizes, int n_in,
                              void* d_out, int out_size, void* d_ws, size_t ws_size,
                              hipStream_t stream) {
  const float* z   = (const float*)d_in[0];
  const float* emb = (const float*)d_in[1];
  float* out = (float*)d_out;
  char* ws = (char*)d_ws;

  __hip_bfloat16* zf   = (__hip_bfloat16*)(ws + WS_ZF);
  __hip_bfloat16* embb = (__hip_bfloat16*)(ws + WS_EMB);
  float* asum = (float*)(ws + WS_ASUM);
  float* bsum = (float*)(ws + WS_BSUM);
  unsigned long long* pmin = (unsigned long long*)(ws + WS_PMIN);
  int* idxi = (int*)(ws + WS_IDX);
  float* dminf = (float*)(ws + WS_DMIN);
  float* lossacc = (float*)(ws + WS_LOSS);

  k_prep_zf<<<dim3(32, 8, 32), 256, 0, stream>>>(z, zf);
  k_prep_asum<<<128, 256, 0, stream>>>(z, asum);
  k_prep_emb<<<2048, 256, 0, stream>>>(emb, embb, bsum);
  k_gemm<<<dim3(256, PANELS), 256, 0, stream>>>(zf, embb, asum, bsum,
                                                out + OUT_D, pmin);
  k_combine_dmin<<<128, 256, 0, stream>>>(pmin, dminf);
  k_refine<<<8192, 256, 0, stream>>>(out + OUT_D, dminf, z, emb,
                                     out + OUT_IDX, idxi);
  hipMemsetAsync(ws + WS_LOSS, 0, 4, stream);
  k_gather<<<2048, 256, 0, stream>>>(z, emb, idxi, out + OUT_ZQ, lossacc);
  k_loss_final<<<1, 1, 0, stream>>>(lossacc, out + OUT_LOSS);
}

// Round 5
// 1089.936 us; speedup vs baseline: 1.2354x; 1.2354x over previous
//
#include <hip/hip_runtime.h>
#include <hip/hip_bf16.h>

// Problem constants
#define NB     32
#define CDIM   256
#define HWDIM  1024          // 32*32
#define NROWS  32768         // NB*HWDIM
#define NE     8192
#define PANELS 4
#define COLS_PER_PANEL 2048
#define NT_PER_PANEL   16    // 2048/128

// numpy pairwise-sum variant for A = np.sum(zf*zf, axis=1)
#define NP_SUM_VARIANT 0

typedef float f32x4 __attribute__((ext_vector_type(4)));
typedef short bf16x8 __attribute__((ext_vector_type(8)));

// d_out layout (floats): z_q_out | loss | d | indices
#define OUT_ZQ   0ull
#define OUT_LOSS 8388608ull
#define OUT_D    8388609ull
#define OUT_IDX  276824065ull   // 8388609 + 32768*8192

// workspace layout (bytes)
#define WS_ZF    0ull           // [NROWS][256] bf16 (16 MB)
#define WS_EMB   16777216ull    // [NE][256] bf16 (4 MB)
#define WS_ASUM  20971520ull    // [NROWS] f32
#define WS_BSUM  21102592ull    // [NE] f32
#define WS_PMIN  21135360ull    // [PANELS][NROWS] u64 packed (val,idx)
#define WS_IDX   22183936ull    // [NROWS] i32
#define WS_DMIN  22315008ull    // [NROWS] f32
#define WS_LOSS  22446080ull    // f32 accumulator

#define REFINE_DELTA 2e-3f

typedef __attribute__((address_space(1))) const void global_cvoid;
typedef __attribute__((address_space(3))) void lds_void;

__device__ __forceinline__ void gl_lds16(const void* g, void* l) {
  __builtin_amdgcn_global_load_lds((global_cvoid*)g, (lds_void*)l, 16, 0, 0);
}

// ---- prep: transpose z[b][c][hw] -> zf[n][c] (bf16), n = b*1024 + hw ----
__global__ void k_prep_zf(const float* __restrict__ z, __hip_bfloat16* __restrict__ zf) {
  __shared__ float tile[32][33];
  const int b   = blockIdx.z;
  const int c0  = blockIdx.y * 32;
  const int hw0 = blockIdx.x * 32;
  const int tx  = threadIdx.x & 31;
  const int ty  = threadIdx.x >> 5;   // 0..7
  const float* zb = z + (size_t)b * (CDIM * HWDIM);
#pragma unroll
  for (int i = 0; i < 4; ++i) {
    int c = ty + i * 8;
    tile[c][tx] = zb[(size_t)(c0 + c) * HWDIM + hw0 + tx];
  }
  __syncthreads();
#pragma unroll
  for (int i = 0; i < 4; ++i) {
    int row = ty + i * 8;                 // hw-local
    int n = b * HWDIM + hw0 + row;
    zf[(size_t)n * CDIM + c0 + tx] = __float2bfloat16(tile[tx][row]);
  }
}

// ---- prep: A~[n] = sum_c z[n][c]^2 (fast fp32, used only for stored d~) ----
__global__ void k_prep_asum(const float* __restrict__ z, float* __restrict__ asum) {
  const int t   = threadIdx.x;
  const int blk = blockIdx.x;           // 0..127
  const int b   = blk >> 2;
  const int hw0 = (blk & 3) * 256;
  const float* zb = z + (size_t)b * (CDIM * HWDIM) + hw0 + t;
  float s = 0.f;
  for (int c = 0; c < CDIM; ++c) {
    float v = zb[(size_t)c * HWDIM];
    s = fmaf(v, v, s);
  }
  asum[b * HWDIM + hw0 + t] = s;
}

// ---- prep: emb -> bf16, B[e] = sum_c e^2 (fp32) ----
__global__ void k_prep_emb(const float* __restrict__ emb, __hip_bfloat16* __restrict__ embb,
                           float* __restrict__ bsum) {
  const int t = threadIdx.x, lane = t & 63, w = t >> 6;
  const int row = blockIdx.x * 4 + w;
  const float4 v = ((const float4*)(emb + (size_t)row * CDIM))[lane];
  __hip_bfloat16* dst = embb + (size_t)row * CDIM + lane * 4;
  dst[0] = __float2bfloat16(v.x);
  dst[1] = __float2bfloat16(v.y);
  dst[2] = __float2bfloat16(v.z);
  dst[3] = __float2bfloat16(v.w);
  float s = v.x * v.x + v.y * v.y + v.z * v.z + v.w * v.w;
#pragma unroll
  for (int m = 32; m; m >>= 1) s += __shfl_xor(s, m, 64);
  if (lane == 0) bsum[row] = s;
}

// ---- GEMM + d-write + per-row packed argmin (panel-partial) ----
// LDS tiles are XOR-swizzled (chunk ^= row&7) to kill the 16-way bank
// conflict of 128B-stride ds_read_b128 (G4 / T2, rule #21: linear LDS dest
// + inverse-swizzled GLOBAL source + swizzled ds_read address).
__global__ __launch_bounds__(256) void k_gemm(
    const __hip_bfloat16* __restrict__ zf, const __hip_bfloat16* __restrict__ embb,
    const float* __restrict__ asum, const float* __restrict__ bsum,
    float* __restrict__ dmat,                       // d region base
    unsigned long long* __restrict__ pmin) {
  __shared__ __hip_bfloat16 As[128 * 64];
  __shared__ __hip_bfloat16 Bs[128 * 64];
  __shared__ unsigned long long smin[128];
  __shared__ unsigned long long smin2[2][128];

  const int tid = threadIdx.x;
  const int lane = tid & 63;
  const int w = tid >> 6;
  const int wr = w >> 1, wc = w & 1;
  const int l15 = lane & 15, g = lane >> 4;
  const int sw = l15 & 7;                 // read-side XOR swizzle key
  const int row0 = blockIdx.x * 128;
  const int colp = blockIdx.y * COLS_PER_PANEL;

  if (tid < 128) smin[tid] = ~0ull;

  float av[4][4];
#pragma unroll
  for (int m = 0; m < 4; ++m) {
    const f32x4 a4 = *(const f32x4*)(asum + row0 + wr * 64 + m * 16 + g * 4);
#pragma unroll
    for (int r = 0; r < 4; ++r) av[m][r] = a4[r];
  }

  for (int nt = 0; nt < NT_PER_PANEL; ++nt) {
    const int col0 = colp + nt * 128;
    f32x4 acc[4][4];
#pragma unroll
    for (int m = 0; m < 4; ++m)
#pragma unroll
      for (int n = 0; n < 4; ++n) acc[m][n] = (f32x4){0.f, 0.f, 0.f, 0.f};

    float bv[4];
#pragma unroll
    for (int n = 0; n < 4; ++n) bv[n] = bsum[col0 + wc * 64 + n * 16 + l15];

    for (int ks = 0; ks < 4; ++ks) {
      const int k0 = ks * 64;
#pragma unroll
      for (int I = 0; I < 4; ++I) {
        const int boff = I * 4096 + tid * 16;
        const int r   = boff >> 7;          // 128 B per row
        const int ch  = (boff >> 4) & 7;    // physical 16B chunk in row
        const int chs = ch ^ (r & 7);       // logical chunk at this slot
        gl_lds16((const char*)zf   + (size_t)(row0 + r) * 512 + k0 * 2 + chs * 16,
                 (char*)As + boff);
        gl_lds16((const char*)embb + (size_t)(col0 + r) * 512 + k0 * 2 + chs * 16,
                 (char*)Bs + boff);
      }
      __syncthreads();
#pragma unroll
      for (int kk = 0; kk < 2; ++kk) {
        bf16x8 af[4], bfr[4];
#pragma unroll
        for (int m = 0; m < 4; ++m)
          af[m] = *(const bf16x8*)((const char*)As +
                    (wr * 64 + m * 16 + l15) * 128 + (((kk << 2) | g) ^ sw) * 16);
#pragma unroll
        for (int n = 0; n < 4; ++n)
          bfr[n] = *(const bf16x8*)((const char*)Bs +
                    (wc * 64 + n * 16 + l15) * 128 + (((kk << 2) | g) ^ sw) * 16);
#pragma unroll
        for (int m = 0; m < 4; ++m)
#pragma unroll
          for (int n = 0; n < 4; ++n)
            acc[m][n] = __builtin_amdgcn_mfma_f32_16x16x32_bf16(af[m], bfr[n], acc[m][n], 0, 0, 0);
      }
      __syncthreads();
    }

#pragma unroll
    for (int m = 0; m < 4; ++m) {
#pragma unroll
      for (int r = 0; r < 4; ++r) {
        const int rowL = wr * 64 + m * 16 + g * 4 + r;
        const size_t rowbase = (size_t)(row0 + rowL) * NE;
        unsigned long long key = ~0ull;
#pragma unroll
        for (int n = 0; n < 4; ++n) {
          const int col = col0 + wc * 64 + n * 16 + l15;
          const float c = acc[m][n][r];
          const float t = av[m][r] + bv[n];
          const float dv = fmaf(-2.f, c, t);    // t - 2c
          dmat[rowbase + col] = dv;
          unsigned long long k2 =
              ((unsigned long long)__float_as_uint(dv) << 32) | (unsigned)col;
          key = k2 < key ? k2 : key;
        }
#pragma unroll
        for (int s = 1; s < 16; s <<= 1) {
          unsigned long long o = __shfl_xor(key, s, 64);
          key = o < key ? o : key;
        }
        if (l15 == 0) smin2[wc][rowL] = key;
      }
    }
    __syncthreads();
    if (tid < 128) {
      unsigned long long a = smin2[0][tid], b = smin2[1][tid];
      unsigned long long mk = a < b ? a : b;
      if (mk < smin[tid]) smin[tid] = mk;
    }
    __syncthreads();
  }
  if (tid < 128) pmin[(size_t)blockIdx.y * NROWS + row0 + tid] = smin[tid];
}

// ---- combine panel argmins -> per-row min stored-d value (f32) ----
__global__ void k_combine_dmin(const unsigned long long* __restrict__ pmin,
                               float* __restrict__ dminf) {
  const int n = blockIdx.x * 256 + threadIdx.x;
  unsigned long long k = pmin[n];
#pragma unroll
  for (int p = 1; p < PANELS; ++p) {
    unsigned long long o = pmin[(size_t)p * NROWS + n];
    k = o < k ? o : k;
  }
  dminf[n] = __uint_as_float((unsigned)(k >> 32));
}

// ---- refine: replicate numpy f32 argmin exactly ----
// np: d_e = fl32(A - 2*C_e)  (B < ULP/2 vanishes in fl(A+B))
// A  = np.sum(zf*zf, axis=1) pairwise f32 (bit-exact tree below)
// C_e rounded to f32 from exact f64 dot
// winner = lowest e among argmin buckets (np first-index tie-break)
__global__ __launch_bounds__(256) void k_refine(
    const float* __restrict__ dmat, const float* __restrict__ dminf,
    const float* __restrict__ z, const float* __restrict__ emb,
    float* __restrict__ out_idx, int* __restrict__ idx_i) {
  __shared__ float zrow[4][CDIM];
  __shared__ float zsq[4][CDIM];
  const int w = threadIdx.x >> 6, lane = threadIdx.x & 63;
  const int n = blockIdx.x * 4 + w;
  const int b = n >> 10, hw = n & 1023;

  const float* zb = z + (size_t)b * (CDIM * HWDIM) + hw;
#pragma unroll
  for (int j = 0; j < 4; ++j) {
    const float v = zb[(size_t)(lane * 4 + j) * HWDIM];
    zrow[w][lane * 4 + j] = v;
    zsq[w][lane * 4 + j] = v * v;   // RNE mul; LDS round-trip blocks fma-contraction
  }
  __syncthreads();

  // ---- A: numpy pairwise f32, n=256 -> two 128 blocks, each 8-accumulator ----
  float A;
#if NP_SUM_VARIANT == 0
  {
    const float* x = zsq[w];
    const int base = (lane & 8) ? 128 : 0;   // lane groups: 0-7 half0, 8-15 half1
    const int j = lane & 7;
    float r = x[base + j];
#pragma unroll
    for (int i = 8; i < 128; i += 8) r += x[base + i + j];
    // ((r0+r1)+(r2+r3)) + ((r4+r5)+(r6+r7))
    r += __shfl_xor(r, 1, 64);
    r += __shfl_xor(r, 2, 64);
    r += __shfl_xor(r, 4, 64);
    const float h0 = __shfl(r, 0, 64);
    const float h1 = __shfl(r, 8, 64);
    A = h0 + h1;
  }
#else
  {
    const float* x = zsq[w];
    const int base = (lane & 16) ? 128 : 0;
    const int l = lane & 15;
    float s[4];
#pragma unroll
    for (int k = 0; k < 4; ++k)
      s[k] = x[base + 16 * k + l] + x[base + 64 + 16 * k + l];
    float v01 = s[0] + s[1], v23 = s[2] + s[3];
    float r = v01 + v23;
    r += __shfl_xor(r, 8, 64);
    r += __shfl_xor(r, 4, 64);
    r += __shfl_xor(r, 1, 64);
    r += __shfl_xor(r, 2, 64);
    const float h0 = __shfl(r, 0, 64);
    const float h1 = __shfl(r, 16, 64);
    A = h0 + h1;
  }
#endif

  // ---- candidate scan over stored d~, exact bucket argmin ----
  const float thresh = dminf[n] + REFINE_DELTA;
  const float* drow = dmat + (size_t)n * NE;
  const float* zr = &zrow[w][lane * 4];
  unsigned long long best = ~0ull;

  for (int i = 0; i < NE / 64; ++i) {
    const int colbase = i * 64;
    const float v = drow[colbase + lane];
    unsigned long long mask = __ballot(v <= thresh);
    while (mask) {
      const int bpos = (int)__builtin_ctzll(mask);
      mask &= mask - 1;
      const int col = colbase + bpos;
      // 64-lane exact f64 dot: C = z . e
      const float4 ev = ((const float4*)(emb + (size_t)col * CDIM))[lane];
      double acc = (double)zr[0] * (double)ev.x;
      acc = fma((double)zr[1], (double)ev.y, acc);
      acc = fma((double)zr[2], (double)ev.z, acc);
      acc = fma((double)zr[3], (double)ev.w, acc);
#pragma unroll
      for (int s = 1; s < 64; s <<= 1) acc += __shfl_xor(acc, s, 64);
      const float C32 = (float)acc;         // RNE f64->f32
      const float D = A - 2.0f * C32;       // np: fl(A - 2C)
      const unsigned long long key =
          ((unsigned long long)__float_as_uint(D) << 32) | (unsigned)col;
      if (key < best) best = key;
    }
  }
  if (lane == 0) {
    const int bi = (int)(unsigned)(best & 0xffffffffull);
    idx_i[n] = bi;
    out_idx[n] = (float)bi;
  }
}

// ---- gather z_q, straight-through output, loss partial ----
__global__ void k_gather(const float* __restrict__ z, const float* __restrict__ emb,
                         const int* __restrict__ idx_i, float* __restrict__ zq_out,
                         float* __restrict__ loss_acc) {
  float part = 0.f;
  const unsigned stride = gridDim.x * 256u;
  for (unsigned i = blockIdx.x * 256u + threadIdx.x; i < 8388608u; i += stride) {
    const int hw = i & 1023;
    const int c  = (i >> 10) & 255;
    const int b  = i >> 18;
    const int n  = b * HWDIM + hw;
    const int e  = idx_i[n];
    const float zq = emb[(size_t)e * CDIM + c];
    const float zv = z[i];
    zq_out[i] = zv + (zq - zv);       // straight-through, ref rounding order
    const float df = zq - zv;
    part = fmaf(df, df, part);
  }
#pragma unroll
  for (int s = 32; s; s >>= 1) part += __shfl_xor(part, s, 64);
  __shared__ float wsum[4];
  if ((threadIdx.x & 63) == 0) wsum[threadIdx.x >> 6] = part;
  __syncthreads();
  if (threadIdx.x == 0) atomicAdd(loss_acc, wsum[0] + wsum[1] + wsum[2] + wsum[3]);
}

__global__ void k_loss_final(const float* __restrict__ loss_acc, float* __restrict__ out_loss) {
  const float m = *loss_acc / 8388608.0f;
  *out_loss = m + 0.25f * m;
}

extern "C" void kernel_launch(void* const* d_in, const int* in_sizes, int n_in,
                              void* d_out, int out_size, void* d_ws, size_t ws_size,
                              hipStream_t stream) {
  const float* z   = (const float*)d_in[0];
  const float* emb = (const float*)d_in[1];
  float* out = (float*)d_out;
  char* ws = (char*)d_ws;

  __hip_bfloat16* zf   = (__hip_bfloat16*)(ws + WS_ZF);
  __hip_bfloat16* embb = (__hip_bfloat16*)(ws + WS_EMB);
  float* asum = (float*)(ws + WS_ASUM);
  float* bsum = (float*)(ws + WS_BSUM);
  unsigned long long* pmin = (unsigned long long*)(ws + WS_PMIN);
  int* idxi = (int*)(ws + WS_IDX);
  float* dminf = (float*)(ws + WS_DMIN);
  float* lossacc = (float*)(ws + WS_LOSS);

  k_prep_zf<<<dim3(32, 8, 32), 256, 0, stream>>>(z, zf);
  k_prep_asum<<<128, 256, 0, stream>>>(z, asum);
  k_prep_emb<<<2048, 256, 0, stream>>>(emb, embb, bsum);
  k_gemm<<<dim3(256, PANELS), 256, 0, stream>>>(zf, embb, asum, bsum,
                                                out + OUT_D, pmin);
  k_combine_dmin<<<128, 256, 0, stream>>>(pmin, dminf);
  k_refine<<<8192, 256, 0, stream>>>(out + OUT_D, dminf, z, emb,
                                     out + OUT_IDX, idxi);
  hipMemsetAsync(ws + WS_LOSS, 0, 4, stream);
  k_gather<<<2048, 256, 0, stream>>>(z, emb, idxi, out + OUT_ZQ, lossacc);
  k_loss_final<<<1, 1, 0, stream>>>(lossacc, out + OUT_LOSS);
}